// Round 4
// baseline (373.153 us; speedup 1.0000x reference)
//
#include <hip/hip_runtime.h>

// Problem constants (from reference)
#define BSZ 512
#define NC  4
#define NN  16384
#define H2  (0.0078125f * 0.0078125f)   // H*H = 1/16384

#define BLK   256            // threads per block (4 waves)
#define SSEG  4              // segments per sample
#define EPT   (NN / (SSEG * BLK))   // elements per thread = 16
#define BATCH 4              // elements loaded per burst

// Accumulator layout:
// acc[0..9]   = G upper triangle: 00,01,02,03,11,12,13,22,23,33  (no H2)
// acc[10..25] = T[i][m] = acc[10 + 4*i + m]                       (no H2)
__global__ __launch_bounds__(BLK, 4)
void loss_partial(const float* __restrict__ coef,
                  const float* __restrict__ pred,
                  const float* __restrict__ targ,
                  float* __restrict__ ws)
{
    const int seg = blockIdx.x;
    const int b   = blockIdx.y;
    const int tid = threadIdx.x;

    const float* __restrict__ cb = coef + (size_t)b * NN;
    const float* __restrict__ p0 = pred + (size_t)b * NC * NN + 0 * NN;
    const float* __restrict__ p1 = pred + (size_t)b * NC * NN + 1 * NN;
    const float* __restrict__ p2 = pred + (size_t)b * NC * NN + 2 * NN;
    const float* __restrict__ p3 = pred + (size_t)b * NC * NN + 3 * NN;
    const float4* __restrict__ t4 = (const float4*)(targ + (size_t)b * NN * NC);

    float acc[26];
#pragma unroll
    for (int k = 0; k < 26; ++k) acc[k] = 0.f;

    const int segbase = seg * (NN / SSEG);

#pragma unroll
    for (int it = 0; it < EPT / BATCH; ++it) {
        float  c[BATCH], a0[BATCH], a1[BATCH], a2[BATCH], a3[BATCH];
        float4 t[BATCH];
        // issue all 24 loads (all lane-coalesced: consecutive lanes ->
        // consecutive addresses for every instruction, incl. targets)
#pragma unroll
        for (int u = 0; u < BATCH; ++u) {
            const int n = segbase + (it * BATCH + u) * BLK + tid;
            c[u]  = cb[n];
            a0[u] = p0[n];
            a1[u] = p1[n];
            a2[u] = p2[n];
            a3[u] = p3[n];
            t[u]  = t4[n];
        }
        // accumulate
#pragma unroll
        for (int u = 0; u < BATCH; ++u) {
            float cp0 = c[u] * a0[u];
            float cp1 = c[u] * a1[u];
            float cp2 = c[u] * a2[u];
            float cp3 = c[u] * a3[u];
            acc[0]  += cp0 * a0[u]; acc[1]  += cp0 * a1[u];
            acc[2]  += cp0 * a2[u]; acc[3]  += cp0 * a3[u];
            acc[4]  += cp1 * a1[u]; acc[5]  += cp1 * a2[u];
            acc[6]  += cp1 * a3[u];
            acc[7]  += cp2 * a2[u]; acc[8]  += cp2 * a3[u];
            acc[9]  += cp3 * a3[u];
            acc[10] += cp0 * t[u].x; acc[11] += cp0 * t[u].y;
            acc[12] += cp0 * t[u].z; acc[13] += cp0 * t[u].w;
            acc[14] += cp1 * t[u].x; acc[15] += cp1 * t[u].y;
            acc[16] += cp1 * t[u].z; acc[17] += cp1 * t[u].w;
            acc[18] += cp2 * t[u].x; acc[19] += cp2 * t[u].y;
            acc[20] += cp2 * t[u].z; acc[21] += cp2 * t[u].w;
            acc[22] += cp3 * t[u].x; acc[23] += cp3 * t[u].y;
            acc[24] += cp3 * t[u].z; acc[25] += cp3 * t[u].w;
        }
    }

    // Block reduction: wave shuffle -> LDS (4 waves) -> 26 threads write out
    const int lane = tid & 63;
    const int wv   = tid >> 6;
    __shared__ float red[26][4];

#pragma unroll
    for (int k = 0; k < 26; ++k) {
        float v = acc[k];
#pragma unroll
        for (int o = 32; o > 0; o >>= 1) v += __shfl_down(v, o, 64);
        if (lane == 0) red[k][wv] = v;
    }
    __syncthreads();

    if (tid < 26) {
        float v = red[tid][0] + red[tid][1] + red[tid][2] + red[tid][3];
        // transposed layout [seg][k][b] so phase 2 reads are lane-coalesced
        ws[((size_t)seg * 26 + tid) * BSZ + b] = v;
    }
}

// Phase 2: one block, 512 threads, one sample per thread. Sum segment
// partials (coalesced), apply H2, run 4-dim MGS + loss per lane, reduce mean.
__global__ __launch_bounds__(BSZ)
void finalize(const float* __restrict__ ws, float* __restrict__ out)
{
    const int b = threadIdx.x;   // sample index, 0..511

    float s[26];
#pragma unroll
    for (int k = 0; k < 26; ++k) s[k] = 0.f;
#pragma unroll
    for (int seg = 0; seg < SSEG; ++seg)
#pragma unroll
        for (int k = 0; k < 26; ++k)
            s[k] += ws[((size_t)seg * 26 + k) * BSZ + b];
#pragma unroll
    for (int k = 0; k < 26; ++k) s[k] *= H2;

    float Gm[4][4];
    Gm[0][0] = s[0];
    Gm[0][1] = Gm[1][0] = s[1];
    Gm[0][2] = Gm[2][0] = s[2];
    Gm[0][3] = Gm[3][0] = s[3];
    Gm[1][1] = s[4];
    Gm[1][2] = Gm[2][1] = s[5];
    Gm[1][3] = Gm[3][1] = s[6];
    Gm[2][2] = s[7];
    Gm[2][3] = Gm[3][2] = s[8];
    Gm[3][3] = s[9];

    float Tm[4][4];
#pragma unroll
    for (int i = 0; i < 4; ++i)
#pragma unroll
        for (int m = 0; m < 4; ++m) Tm[i][m] = s[10 + 4 * i + m];

    // Modified Gram-Schmidt in 4-dim coefficient space.
    float u[4][4];
#pragma unroll
    for (int j = 0; j < 4; ++j) {
        float w[4];
#pragma unroll
        for (int i = 0; i < 4; ++i) w[i] = (i == j) ? 1.f : 0.f;
#pragma unroll
        for (int k = 0; k < 4; ++k) {
            if (k < j) {
                float proj = 0.f;
#pragma unroll
                for (int i = 0; i < 4; ++i) {
                    float gu = 0.f;
#pragma unroll
                    for (int l = 0; l < 4; ++l) gu += Gm[i][l] * u[k][l];
                    proj += w[i] * gu;
                }
#pragma unroll
                for (int i = 0; i < 4; ++i) w[i] -= proj * u[k][i];
            }
        }
        float n2 = 0.f;
#pragma unroll
        for (int i = 0; i < 4; ++i) {
            float gw = 0.f;
#pragma unroll
            for (int l = 0; l < 4; ++l) gw += Gm[i][l] * w[l];
            n2 += w[i] * gw;
        }
        float sc = (n2 > 0.f) ? rsqrtf(n2) : 1.f;
#pragma unroll
        for (int i = 0; i < 4; ++i) u[j][i] = w[i] * sc;
    }

    float ssum = 0.f;
#pragma unroll
    for (int c = 0; c < 4; ++c) {
#pragma unroll
        for (int m = 0; m < 4; ++m) {
            float M = 0.f;
#pragma unroll
            for (int i = 0; i < 4; ++i) M += u[c][i] * Tm[i][m];
            ssum += M * M;
        }
    }
    float ps = (4.f - ssum) * 0.25f;

    // mean over 512 lanes
#pragma unroll
    for (int o = 32; o > 0; o >>= 1) ps += __shfl_down(ps, o, 64);
    __shared__ float red[8];
    if ((b & 63) == 0) red[b >> 6] = ps;
    __syncthreads();
    if (b == 0) {
        float t = 0.f;
#pragma unroll
        for (int w = 0; w < 8; ++w) t += red[w];
        out[0] = t / (float)BSZ;
    }
}

extern "C" void kernel_launch(void* const* d_in, const int* in_sizes, int n_in,
                              void* d_out, int out_size, void* d_ws, size_t ws_size,
                              hipStream_t stream)
{
    const float* coef = (const float*)d_in[0];   // (B, N)
    const float* pred = (const float*)d_in[1];   // (B, C, N)
    const float* targ = (const float*)d_in[2];   // (B, N, C)
    float* out = (float*)d_out;                  // scalar
    float* ws  = (float*)d_ws;                   // SSEG*26*BSZ floats = 213 KB

    dim3 grid(SSEG, BSZ);
    loss_partial<<<grid, BLK, 0, stream>>>(coef, pred, targ, ws);
    finalize<<<1, BSZ, 0, stream>>>(ws, out);
}

// Round 5
// 304.586 us; speedup vs baseline: 1.2251x; 1.2251x over previous
//
#include <hip/hip_runtime.h>

// Problem constants (from reference)
#define BSZ 512
#define NC  4
#define NN  16384
#define H2  (0.0078125f * 0.0078125f)   // H*H = 1/16384

#define BLK   256            // threads per block (4 waves)
#define SSEG  4              // segments per sample
#define NG    (NN / 4)       // float4 groups per sample = 4096
#define GSEG  (NG / SSEG)    // groups per segment = 1024
#define ITERS (GSEG / BLK)   // groups per thread = 4

// Accumulator layout (H2 deferred to finalize):
// acc[0..9]   = G upper triangle: 00,01,02,03,11,12,13,22,23,33
// acc[10..25] = T[i][m] = acc[10 + 4*i + m]
__device__ __forceinline__ void accum_elem(float c,
                                           float p0, float p1, float p2, float p3,
                                           float tx, float ty, float tz, float tw,
                                           float* acc)
{
    float cp0 = c * p0, cp1 = c * p1, cp2 = c * p2, cp3 = c * p3;
    acc[0]  += cp0 * p0;  acc[1]  += cp0 * p1;  acc[2]  += cp0 * p2;  acc[3]  += cp0 * p3;
    acc[4]  += cp1 * p1;  acc[5]  += cp1 * p2;  acc[6]  += cp1 * p3;
    acc[7]  += cp2 * p2;  acc[8]  += cp2 * p3;
    acc[9]  += cp3 * p3;
    acc[10] += cp0 * tx;  acc[11] += cp0 * ty;  acc[12] += cp0 * tz;  acc[13] += cp0 * tw;
    acc[14] += cp1 * tx;  acc[15] += cp1 * ty;  acc[16] += cp1 * tz;  acc[17] += cp1 * tw;
    acc[18] += cp2 * tx;  acc[19] += cp2 * ty;  acc[20] += cp2 * tz;  acc[21] += cp2 * tw;
    acc[22] += cp3 * tx;  acc[23] += cp3 * ty;  acc[24] += cp3 * tz;  acc[25] += cp3 * tw;
}

// Phase 1: block = (segment, sample). Each thread processes ITERS float4
// groups; per iteration, 10 float4 loads (1.25 KB) go in flight together.
// __launch_bounds__(256,2): 256-VGPR cap -> ~90-reg live set stays in
// registers, no spill, loads not serialized by the allocator.
__global__ __launch_bounds__(BLK, 2)
void loss_partial(const float* __restrict__ coef,
                  const float* __restrict__ pred,
                  const float* __restrict__ targ,
                  float* __restrict__ ws)
{
    const int seg = blockIdx.x;
    const int b   = blockIdx.y;
    const int tid = threadIdx.x;

    const float4* __restrict__ c4 = (const float4*)(coef + (size_t)b * NN);
    const float4* __restrict__ q0 = (const float4*)(pred + (size_t)b * NC * NN + 0 * NN);
    const float4* __restrict__ q1 = (const float4*)(pred + (size_t)b * NC * NN + 1 * NN);
    const float4* __restrict__ q2 = (const float4*)(pred + (size_t)b * NC * NN + 2 * NN);
    const float4* __restrict__ q3 = (const float4*)(pred + (size_t)b * NC * NN + 3 * NN);
    const float4* __restrict__ t4 = (const float4*)(targ + (size_t)b * NN * NC);

    float acc[26];
#pragma unroll
    for (int k = 0; k < 26; ++k) acc[k] = 0.f;

#pragma unroll 1
    for (int it = 0; it < ITERS; ++it) {
        const int g = seg * GSEG + it * BLK + tid;
        // 10 float4 loads, all issued before any use
        float4 cc = c4[g];
        float4 a0 = q0[g];
        float4 a1 = q1[g];
        float4 a2 = q2[g];
        float4 a3 = q3[g];
        float4 t0 = t4[4 * g + 0];
        float4 t1 = t4[4 * g + 1];
        float4 t2 = t4[4 * g + 2];
        float4 t3 = t4[4 * g + 3];

        accum_elem(cc.x, a0.x, a1.x, a2.x, a3.x, t0.x, t0.y, t0.z, t0.w, acc);
        accum_elem(cc.y, a0.y, a1.y, a2.y, a3.y, t1.x, t1.y, t1.z, t1.w, acc);
        accum_elem(cc.z, a0.z, a1.z, a2.z, a3.z, t2.x, t2.y, t2.z, t2.w, acc);
        accum_elem(cc.w, a0.w, a1.w, a2.w, a3.w, t3.x, t3.y, t3.z, t3.w, acc);
    }

    // Block reduction: wave shuffle -> LDS (4 waves) -> 26 threads write out
    const int lane = tid & 63;
    const int wv   = tid >> 6;
    __shared__ float red[26][4];

#pragma unroll
    for (int k = 0; k < 26; ++k) {
        float v = acc[k];
#pragma unroll
        for (int o = 32; o > 0; o >>= 1) v += __shfl_down(v, o, 64);
        if (lane == 0) red[k][wv] = v;
    }
    __syncthreads();

    if (tid < 26) {
        float v = red[tid][0] + red[tid][1] + red[tid][2] + red[tid][3];
        // transposed layout [seg][k][b] so phase 2 reads are lane-coalesced
        ws[((size_t)seg * 26 + tid) * BSZ + b] = v;
    }
}

// Phase 2: one block, 512 threads, one sample per thread. Sum segment
// partials (coalesced), apply H2, run 4-dim MGS + loss per lane, reduce mean.
__global__ __launch_bounds__(BSZ)
void finalize(const float* __restrict__ ws, float* __restrict__ out)
{
    const int b = threadIdx.x;   // sample index, 0..511

    float s[26];
#pragma unroll
    for (int k = 0; k < 26; ++k) s[k] = 0.f;
#pragma unroll
    for (int seg = 0; seg < SSEG; ++seg)
#pragma unroll
        for (int k = 0; k < 26; ++k)
            s[k] += ws[((size_t)seg * 26 + k) * BSZ + b];
#pragma unroll
    for (int k = 0; k < 26; ++k) s[k] *= H2;

    float Gm[4][4];
    Gm[0][0] = s[0];
    Gm[0][1] = Gm[1][0] = s[1];
    Gm[0][2] = Gm[2][0] = s[2];
    Gm[0][3] = Gm[3][0] = s[3];
    Gm[1][1] = s[4];
    Gm[1][2] = Gm[2][1] = s[5];
    Gm[1][3] = Gm[3][1] = s[6];
    Gm[2][2] = s[7];
    Gm[2][3] = Gm[3][2] = s[8];
    Gm[3][3] = s[9];

    float Tm[4][4];
#pragma unroll
    for (int i = 0; i < 4; ++i)
#pragma unroll
        for (int m = 0; m < 4; ++m) Tm[i][m] = s[10 + 4 * i + m];

    // Modified Gram-Schmidt in 4-dim coefficient space.
    float u[4][4];
#pragma unroll
    for (int j = 0; j < 4; ++j) {
        float w[4];
#pragma unroll
        for (int i = 0; i < 4; ++i) w[i] = (i == j) ? 1.f : 0.f;
#pragma unroll
        for (int k = 0; k < 4; ++k) {
            if (k < j) {
                float proj = 0.f;
#pragma unroll
                for (int i = 0; i < 4; ++i) {
                    float gu = 0.f;
#pragma unroll
                    for (int l = 0; l < 4; ++l) gu += Gm[i][l] * u[k][l];
                    proj += w[i] * gu;
                }
#pragma unroll
                for (int i = 0; i < 4; ++i) w[i] -= proj * u[k][i];
            }
        }
        float n2 = 0.f;
#pragma unroll
        for (int i = 0; i < 4; ++i) {
            float gw = 0.f;
#pragma unroll
            for (int l = 0; l < 4; ++l) gw += Gm[i][l] * w[l];
            n2 += w[i] * gw;
        }
        float sc = (n2 > 0.f) ? rsqrtf(n2) : 1.f;
#pragma unroll
        for (int i = 0; i < 4; ++i) u[j][i] = w[i] * sc;
    }

    float ssum = 0.f;
#pragma unroll
    for (int c = 0; c < 4; ++c) {
#pragma unroll
        for (int m = 0; m < 4; ++m) {
            float M = 0.f;
#pragma unroll
            for (int i = 0; i < 4; ++i) M += u[c][i] * Tm[i][m];
            ssum += M * M;
        }
    }
    float ps = (4.f - ssum) * 0.25f;

    // mean over 512 lanes
#pragma unroll
    for (int o = 32; o > 0; o >>= 1) ps += __shfl_down(ps, o, 64);
    __shared__ float red[8];
    if ((b & 63) == 0) red[b >> 6] = ps;
    __syncthreads();
    if (b == 0) {
        float t = 0.f;
#pragma unroll
        for (int w = 0; w < 8; ++w) t += red[w];
        out[0] = t / (float)BSZ;
    }
}

extern "C" void kernel_launch(void* const* d_in, const int* in_sizes, int n_in,
                              void* d_out, int out_size, void* d_ws, size_t ws_size,
                              hipStream_t stream)
{
    const float* coef = (const float*)d_in[0];   // (B, N)
    const float* pred = (const float*)d_in[1];   // (B, C, N)
    const float* targ = (const float*)d_in[2];   // (B, N, C)
    float* out = (float*)d_out;                  // scalar
    float* ws  = (float*)d_ws;                   // SSEG*26*BSZ floats = 213 KB

    dim3 grid(SSEG, BSZ);
    loss_partial<<<grid, BLK, 0, stream>>>(coef, pred, targ, ws);
    finalize<<<1, BSZ, 0, stream>>>(ws, out);
}

// Round 6
// 304.072 us; speedup vs baseline: 1.2272x; 1.0017x over previous
//
#include <hip/hip_runtime.h>
#include <stdint.h>

// Problem constants (from reference)
#define BSZ 512
#define NC  4
#define NN  16384
#define H2  (0.0078125f * 0.0078125f)   // H*H = 1/16384

#define BLK   256                 // threads per block (4 waves)
#define SSEG  4                   // segments per sample
#define TILE  1024                // elements per tile
#define TPB   (NN / SSEG / TILE)  // tiles per block = 4
// per-buffer floats: coef TILE + pred NC*TILE + targ NC*TILE = 9216 (36 KB)
#define BUF_F (TILE + NC * TILE + NC * TILE)

// Async global->LDS DMA, 16 B per lane. LDS dest is wave-uniform base +
// lane*16 (m104/m108) — our staging addresses respect that by construction.
__device__ __forceinline__ void dma16(const float* g, float* l)
{
    __builtin_amdgcn_global_load_lds(
        (const __attribute__((address_space(1))) uint32_t*)g,
        (__attribute__((address_space(3))) uint32_t*)l,
        16, 0, 0);
}

// Accumulator layout (H2 deferred to finalize):
// acc[0..9]   = G upper triangle: 00,01,02,03,11,12,13,22,23,33
// acc[10..25] = T[i][m] = acc[10 + 4*i + m]
__global__ __launch_bounds__(BLK, 2)
void loss_partial(const float* __restrict__ coef,
                  const float* __restrict__ pred,
                  const float* __restrict__ targ,
                  float* __restrict__ ws)
{
    const int seg = blockIdx.x;
    const int b   = blockIdx.y;
    const int tid = threadIdx.x;

    const float* __restrict__ cb = coef + (size_t)b * NN;
    const float* __restrict__ pb = pred + (size_t)b * NC * NN;
    const float* __restrict__ tg = targ + (size_t)b * NN * NC;

    const int segbase = seg * (NN / SSEG);   // element base of this segment

    __shared__ float buf[2][BUF_F];

    float acc[26];
#pragma unroll
    for (int k = 0; k < 26; ++k) acc[k] = 0.f;

    // ---- staging: 9 DMA issues per thread per tile ----
    auto stage = [&](int t, int q) {
        const int E = segbase + t * TILE;     // global element base of tile
        float* bc = &buf[q][0];
        float* bp = &buf[q][TILE];
        float* bt = &buf[q][TILE + NC * TILE];
        // coef: 4 KB = 256 chunks, 1 call
        dma16(cb + E + tid * 4, bc + tid * 4);
        // pred rows: 4 KB each, 1 call per row
#pragma unroll
        for (int j = 0; j < NC; ++j)
            dma16(pb + (size_t)j * NN + E + tid * 4, bp + j * TILE + tid * 4);
        // targ: 16 KB contiguous, 4 calls
#pragma unroll
        for (int i = 0; i < 4; ++i) {
            const int c = i * BLK + tid;      // 16B-chunk index in tile
            dma16(tg + (size_t)E * NC + c * 4, bt + c * 4);
        }
    };

    // ---- compute: stride-256 element mapping (bank-conflict-free) ----
    auto compute = [&](int q) {
        const float* bc = &buf[q][0];
        const float* bp = &buf[q][TILE];
        const float* bt = &buf[q][TILE + NC * TILE];
#pragma unroll
        for (int u = 0; u < TILE / BLK; ++u) {
            const int e = u * BLK + tid;
            float c  = bc[e];
            float p0 = bp[0 * TILE + e];
            float p1 = bp[1 * TILE + e];
            float p2 = bp[2 * TILE + e];
            float p3 = bp[3 * TILE + e];
            float4 tv = ((const float4*)bt)[e];
            float cp0 = c * p0, cp1 = c * p1, cp2 = c * p2, cp3 = c * p3;
            acc[0]  += cp0 * p0;  acc[1]  += cp0 * p1;
            acc[2]  += cp0 * p2;  acc[3]  += cp0 * p3;
            acc[4]  += cp1 * p1;  acc[5]  += cp1 * p2;
            acc[6]  += cp1 * p3;
            acc[7]  += cp2 * p2;  acc[8]  += cp2 * p3;
            acc[9]  += cp3 * p3;
            acc[10] += cp0 * tv.x; acc[11] += cp0 * tv.y;
            acc[12] += cp0 * tv.z; acc[13] += cp0 * tv.w;
            acc[14] += cp1 * tv.x; acc[15] += cp1 * tv.y;
            acc[16] += cp1 * tv.z; acc[17] += cp1 * tv.w;
            acc[18] += cp2 * tv.x; acc[19] += cp2 * tv.y;
            acc[20] += cp2 * tv.z; acc[21] += cp2 * tv.w;
            acc[22] += cp3 * tv.x; acc[23] += cp3 * tv.y;
            acc[24] += cp3 * tv.z; acc[25] += cp3 * tv.w;
        }
    };

    // ---- double-buffered pipeline ----
    stage(0, 0);
#pragma unroll 1
    for (int t = 0; t < TPB; ++t) {
        __syncthreads();                 // vmcnt(0) drain -> tile t resident
        if (t + 1 < TPB) stage(t + 1, (t + 1) & 1);
        compute(t & 1);
    }

    // ---- block reduction: wave shuffle -> LDS (4 waves) -> write out ----
    const int lane = tid & 63;
    const int wv   = tid >> 6;
    __shared__ float red[26][4];

#pragma unroll
    for (int k = 0; k < 26; ++k) {
        float v = acc[k];
#pragma unroll
        for (int o = 32; o > 0; o >>= 1) v += __shfl_down(v, o, 64);
        if (lane == 0) red[k][wv] = v;
    }
    __syncthreads();

    if (tid < 26) {
        float v = red[tid][0] + red[tid][1] + red[tid][2] + red[tid][3];
        // transposed layout [seg][k][b] so phase 2 reads are lane-coalesced
        ws[((size_t)seg * 26 + tid) * BSZ + b] = v;
    }
}

// Phase 2: one block, 512 threads, one sample per thread. Sum segment
// partials (coalesced), apply H2, run 4-dim MGS + loss per lane, reduce mean.
__global__ __launch_bounds__(BSZ)
void finalize(const float* __restrict__ ws, float* __restrict__ out)
{
    const int b = threadIdx.x;   // sample index, 0..511

    float s[26];
#pragma unroll
    for (int k = 0; k < 26; ++k) s[k] = 0.f;
#pragma unroll
    for (int seg = 0; seg < SSEG; ++seg)
#pragma unroll
        for (int k = 0; k < 26; ++k)
            s[k] += ws[((size_t)seg * 26 + k) * BSZ + b];
#pragma unroll
    for (int k = 0; k < 26; ++k) s[k] *= H2;

    float Gm[4][4];
    Gm[0][0] = s[0];
    Gm[0][1] = Gm[1][0] = s[1];
    Gm[0][2] = Gm[2][0] = s[2];
    Gm[0][3] = Gm[3][0] = s[3];
    Gm[1][1] = s[4];
    Gm[1][2] = Gm[2][1] = s[5];
    Gm[1][3] = Gm[3][1] = s[6];
    Gm[2][2] = s[7];
    Gm[2][3] = Gm[3][2] = s[8];
    Gm[3][3] = s[9];

    float Tm[4][4];
#pragma unroll
    for (int i = 0; i < 4; ++i)
#pragma unroll
        for (int m = 0; m < 4; ++m) Tm[i][m] = s[10 + 4 * i + m];

    // Modified Gram-Schmidt in 4-dim coefficient space.
    float u[4][4];
#pragma unroll
    for (int j = 0; j < 4; ++j) {
        float w[4];
#pragma unroll
        for (int i = 0; i < 4; ++i) w[i] = (i == j) ? 1.f : 0.f;
#pragma unroll
        for (int k = 0; k < 4; ++k) {
            if (k < j) {
                float proj = 0.f;
#pragma unroll
                for (int i = 0; i < 4; ++i) {
                    float gu = 0.f;
#pragma unroll
                    for (int l = 0; l < 4; ++l) gu += Gm[i][l] * u[k][l];
                    proj += w[i] * gu;
                }
#pragma unroll
                for (int i = 0; i < 4; ++i) w[i] -= proj * u[k][i];
            }
        }
        float n2 = 0.f;
#pragma unroll
        for (int i = 0; i < 4; ++i) {
            float gw = 0.f;
#pragma unroll
            for (int l = 0; l < 4; ++l) gw += Gm[i][l] * w[l];
            n2 += w[i] * gw;
        }
        float sc = (n2 > 0.f) ? rsqrtf(n2) : 1.f;
#pragma unroll
        for (int i = 0; i < 4; ++i) u[j][i] = w[i] * sc;
    }

    float ssum = 0.f;
#pragma unroll
    for (int c = 0; c < 4; ++c) {
#pragma unroll
        for (int m = 0; m < 4; ++m) {
            float M = 0.f;
#pragma unroll
            for (int i = 0; i < 4; ++i) M += u[c][i] * Tm[i][m];
            ssum += M * M;
        }
    }
    float ps = (4.f - ssum) * 0.25f;

    // mean over 512 lanes
#pragma unroll
    for (int o = 32; o > 0; o >>= 1) ps += __shfl_down(ps, o, 64);
    __shared__ float red[8];
    if ((b & 63) == 0) red[b >> 6] = ps;
    __syncthreads();
    if (b == 0) {
        float t = 0.f;
#pragma unroll
        for (int w = 0; w < 8; ++w) t += red[w];
        out[0] = t / (float)BSZ;
    }
}

extern "C" void kernel_launch(void* const* d_in, const int* in_sizes, int n_in,
                              void* d_out, int out_size, void* d_ws, size_t ws_size,
                              hipStream_t stream)
{
    const float* coef = (const float*)d_in[0];   // (B, N)
    const float* pred = (const float*)d_in[1];   // (B, C, N)
    const float* targ = (const float*)d_in[2];   // (B, N, C)
    float* out = (float*)d_out;                  // scalar
    float* ws  = (float*)d_ws;                   // SSEG*26*BSZ floats = 213 KB

    dim3 grid(SSEG, BSZ);
    loss_partial<<<grid, BLK, 0, stream>>>(coef, pred, targ, ws);
    finalize<<<1, BSZ, 0, stream>>>(ws, out);
}